// Round 1
// 589.888 us; speedup vs baseline: 1.7714x; 1.7714x over previous
//
#include <hip/hip_runtime.h>
#include <math.h>

#define B 8
#define C 256
#define H 160
#define W 160
#define HW (H*W)
#define HIDDEN 16

#define CCHUNK 64              // channels per k1 block
#define NCHUNK (C/CCHUNK)      // 4 channel chunks
#define PBB    (HW/256)        // 100 pixel-blocks per batch (HW%256==0)
#define PBLKS  (B*PBB)         // 800 pixel-blocks total

// ---------------- k1: Sobel + partial reductions (no atomics) ----------------
// grid = PBLKS*NCHUNK. Block (pblk,chunk): 256 pixels x 64 channels.
// part_c[(blk*4+wid)*CCHUNK + cc] = wave-sum of g for channel chunk*64+cc
// part_s[(chunk*B+b)*4*HW + plane*HW + hw] = per-chunk {sum_x,max_x,sum_g,max_g}
__global__ __launch_bounds__(256) void k1_sobel_stats(
    const float* __restrict__ x, float* __restrict__ part_c,
    float* __restrict__ part_s)
{
    const int tid   = threadIdx.x;
    const int blk   = blockIdx.x;
    const int chunk = blk & (NCHUNK-1);
    const int pblk  = blk >> 2;               // [0, PBLKS)
    const int p     = pblk * 256 + tid;       // pixel in [0, B*HW)
    const int b     = p / HW;                 // whole block shares b
    const int hw    = p % HW;
    const int h     = hw / W;
    const int w     = hw % W;
    const bool up = (h > 0), dn = (h < H-1), lf = (w > 0), rt = (w < W-1);

    const float* xp = x + (size_t)(b*C + chunk*CCHUNK) * HW + hw;
    float* pc = part_c + ((size_t)blk*4 + (tid >> 6)) * CCHUNK;

    float sum_x = 0.f, max_x = -INFINITY, sum_g = 0.f, max_g = -INFINITY;

    #pragma unroll 4
    for (int cc = 0; cc < CCHUNK; ++cc) {
        const float* q = xp + (size_t)cc * HW;
        float a0 = (up&&lf) ? q[-W-1] : 0.f;
        float a1 =  up      ? q[-W]   : 0.f;
        float a2 = (up&&rt) ? q[-W+1] : 0.f;
        float b0 =  lf      ? q[-1]   : 0.f;
        float b1 =            q[0];
        float b2 =  rt      ? q[1]    : 0.f;
        float c0 = (dn&&lf) ? q[W-1]  : 0.f;
        float c1 =  dn      ? q[W]    : 0.f;
        float c2 = (dn&&rt) ? q[W+1]  : 0.f;

        // cross-correlation with kx, ky (no flip in XLA conv)
        float gx = 0.25f * ((a0 - a2) + 2.f*(b0 - b2) + (c0 - c2));
        float gy = 0.25f * ((a0 + 2.f*a1 + a2) - (c0 + 2.f*c1 + c2));
        float g  = sqrtf(gx*gx + gy*gy + 1e-12f);

        sum_x += b1;  max_x = fmaxf(max_x, b1);
        sum_g += g;   max_g = fmaxf(max_g, g);

        // wave-level reduce of g over 64 pixels -> private slot (no atomic)
        float gs = g;
        #pragma unroll
        for (int off = 32; off; off >>= 1) gs += __shfl_xor(gs, off, 64);
        if ((tid & 63) == 0) pc[cc] = gs;
    }

    float* sp = part_s + (size_t)(chunk*B + b) * 4 * HW + hw;
    sp[0]      = sum_x;
    sp[HW]     = max_x;
    sp[2*HW]   = sum_g;
    sp[3*HW]   = max_g;
}

// ---------------- k1b: fold 4 channel-chunk partials into s_in ----------------
__global__ __launch_bounds__(256) void k1b_combine(
    const float* __restrict__ part_s, float* __restrict__ s_in)
{
    const int p  = blockIdx.x * 256 + threadIdx.x;   // [0, B*HW)
    const int b  = p / HW;
    const int hw = p % HW;

    float sx = 0.f, mx = -INFINITY, sg = 0.f, mg = -INFINITY;
    #pragma unroll
    for (int chunk = 0; chunk < NCHUNK; ++chunk) {
        const float* sp = part_s + (size_t)(chunk*B + b) * 4 * HW + hw;
        sx += sp[0];
        mx  = fmaxf(mx, sp[HW]);
        sg += sp[2*HW];
        mg  = fmaxf(mg, sp[3*HW]);
    }
    float* o = s_in + (size_t)b * 4 * HW + hw;
    o[0]      = sx * (1.f/C);
    o[HW]     = mx;
    o[2*HW]   = sg * (1.f/C);
    o[3*HW]   = mg;
}

// ---------------- k2: reduce c partials + channel-gate MLP ----------------
// grid = B blocks; block b reduces 400 partials per channel, then the MLP.
__global__ __launch_bounds__(256) void k2_mlp(
    const float* __restrict__ part_c, const float* __restrict__ w1,
    const float* __restrict__ w2, const float* __restrict__ beta,
    float* __restrict__ chanfac)
{
    __shared__ float cv[C];
    __shared__ float hb[HIDDEN];
    const int b   = blockIdx.x;
    const int tid = threadIdx.x;       // = channel index
    const int chunk = tid >> 6;        // which CCHUNK this channel lives in
    const int cc    = tid & 63;

    // sum over 100 pixel-blocks x 4 waves for this (b, channel)
    float acc = 0.f;
    for (int pbb = 0; pbb < PBB; ++pbb) {
        const int blk = (b*PBB + pbb) * NCHUNK + chunk;
        const float* pcb = part_c + (size_t)blk * 4 * CCHUNK + cc;
        acc += pcb[0] + pcb[CCHUNK] + pcb[2*CCHUNK] + pcb[3*CCHUNK];
    }
    cv[tid] = acc * (1.f/(float)HW);
    __syncthreads();

    if (tid < HIDDEN) {
        float a = 0.f;
        for (int c = 0; c < C; ++c) a += cv[c] * w1[tid*C + c];
        hb[tid] = fmaxf(a, 0.f);
    }
    __syncthreads();

    float bt = beta[0];
    float sb = (bt > 20.f) ? bt : log1pf(expf(bt));   // softplus
    float a = 0.f;
    #pragma unroll
    for (int j = 0; j < HIDDEN; ++j) a += hb[j] * w2[tid*HIDDEN + j];
    float gate = 1.f / (1.f + expf(-a));
    chanfac[b*C + tid] = 1.f + sb * gate;
}

// ---------------- k3: 7x7 spatial conv + sigmoid ----------------
__global__ __launch_bounds__(256) void k3_spatial(
    const float* __restrict__ s_in, const float* __restrict__ sw,
    const float* __restrict__ sbias, const float* __restrict__ alpha,
    float* __restrict__ sfac)
{
    __shared__ float wgt[4*49];
    const int tid = threadIdx.x;
    if (tid < 196) wgt[tid] = sw[tid];
    __syncthreads();

    const int p  = blockIdx.x * 256 + tid;   // pixel in [0, B*HW)
    const int b  = p / HW;
    const int hw = p % HW;
    const int h  = hw / W;
    const int w  = hw % W;

    const float* base = s_in + (size_t)b * 4 * HW;
    float acc = 0.f;
    for (int ci = 0; ci < 4; ++ci) {
        const float* pl = base + ci*HW;
        #pragma unroll
        for (int i = 0; i < 7; ++i) {
            int hh = h + i - 3;
            if (hh < 0 || hh >= H) continue;
            const float* row = pl + hh*W;
            const float* wr  = wgt + ci*49 + i*7;
            #pragma unroll
            for (int j = 0; j < 7; ++j) {
                int ww = w + j - 3;
                float v = (ww >= 0 && ww < W) ? row[ww] : 0.f;
                acc = fmaf(wr[j], v, acc);
            }
        }
    }
    float al = alpha[0];
    float sa = (al > 20.f) ? al : log1pf(expf(al));   // softplus
    float sg = 1.f / (1.f + expf(-(acc + sbias[0])));
    sfac[p] = 1.f + sa * sg;
}

// ---------------- k4: elementwise combine (float4) ----------------
__global__ __launch_bounds__(256) void k4_combine(
    const float4* __restrict__ x4, const float* __restrict__ sfac,
    const float* __restrict__ chanfac, float4* __restrict__ out4)
{
    const int i = blockIdx.x * 256 + threadIdx.x;  // float4 index
    const int e  = i * 4;
    const int bc = e / HW;          // b*C + c
    const int hw = e % HW;          // aligned to 4 (HW % 4 == 0)
    const int b  = bc / C;

    const float cf = chanfac[bc];
    const float4 s = *(const float4*)&sfac[b*HW + hw];
    float4 xv = x4[i];
    float4 o;
    o.x = xv.x * s.x * cf;
    o.y = xv.y * s.y * cf;
    o.z = xv.z * s.z * cf;
    o.w = xv.w * s.w * cf;
    out4[i] = o;
}

extern "C" void kernel_launch(void* const* d_in, const int* in_sizes, int n_in,
                              void* d_out, int out_size, void* d_ws, size_t ws_size,
                              hipStream_t stream) {
    const float* x     = (const float*)d_in[0];
    const float* w1    = (const float*)d_in[1];
    const float* w2    = (const float*)d_in[2];
    const float* sw    = (const float*)d_in[3];
    const float* sbias = (const float*)d_in[4];
    const float* alpha = (const float*)d_in[5];
    const float* beta  = (const float*)d_in[6];
    float* out = (float*)d_out;

    float* ws = (float*)d_ws;
    // workspace layout (floats):
    float* part_c  = ws;                                   // PBLKS*NCHUNK*4*CCHUNK = 819200
    float* part_s  = part_c + (size_t)PBLKS*NCHUNK*4*CCHUNK;       // NCHUNK*B*4*HW = 3276800
    float* s_in    = part_s + (size_t)NCHUNK*B*4*HW;               // B*4*HW = 819200
    float* sfac    = s_in   + (size_t)B*4*HW;                      // B*HW   = 204800
    float* chanfac = sfac   + (size_t)B*HW;                        // B*C    = 2048
    // total = 5,122,048 floats ~= 20.5 MB

    k1_sobel_stats<<<PBLKS*NCHUNK, 256, 0, stream>>>(x, part_c, part_s);
    k1b_combine  <<<(B*HW)/256,   256, 0, stream>>>(part_s, s_in);
    k2_mlp       <<<B,            256, 0, stream>>>(part_c, w1, w2, beta, chanfac);
    k3_spatial   <<<(B*HW)/256,   256, 0, stream>>>(s_in, sw, sbias, alpha, sfac);
    k4_combine   <<<(B*C*HW/4)/256, 256, 0, stream>>>((const float4*)x, sfac, chanfac, (float4*)out);
}

// Round 2
// 478.436 us; speedup vs baseline: 2.1840x; 1.2330x over previous
//
#include <hip/hip_runtime.h>
#include <math.h>

#define B 8
#define C 256
#define H 160
#define W 160
#define HW (H*W)
#define HIDDEN 16

#define CCHUNK 32               // channels per k1 block
#define NCHUNK (C/CCHUNK)       // 8 channel chunks
#define W4 (W/4)                // 40 float4 per row
#define F4B (HW/4)              // 6400 float4 per (b,c) plane
#define PBB (F4B/256)           // 25 pixel-blocks per batch
#define PBLKS (B*PBB)           // 200 pixel-blocks total

// ---------------- k1: Sobel + partial reductions, 4 px/thread ----------------
// grid = PBLKS*NCHNK. Block (pblk,chunk): 256 threads x 4 px x CCHUNK channels.
// part_c[(blk*4+wid)*CCHUNK+cc] = wave-sum of g (256 px) for channel chunk*32+cc
// part_s[(chunk*B+b)*4*HW + plane*HW + hw] = per-chunk {sum_x,max_x,sum_g,max_g}
__global__ __launch_bounds__(256) void k1_sobel_stats(
    const float* __restrict__ x, float* __restrict__ part_c,
    float* __restrict__ part_s)
{
    const int tid   = threadIdx.x;
    const int blk   = blockIdx.x;
    const int chunk = blk & (NCHUNK-1);
    const int pblk  = blk >> 3;                 // [0, PBLKS)
    const int f     = pblk * 256 + tid;         // global float4 index
    const int b     = f / F4B;
    const int r     = f % F4B;
    const int h     = r / W4;
    const int w     = (r % W4) * 4;             // leftmost of 4 pixels
    const int hw    = h * W + w;

    const bool up = (h > 0), dn = (h < H-1), lf = (w > 0), rt = (w+4 < W);
    const float upf = up ? 1.f : 0.f, dnf = dn ? 1.f : 0.f;
    const float lff = lf ? 1.f : 0.f, rtf = rt ? 1.f : 0.f;
    const float f_tl = upf*lff, f_tr = upf*rtf;
    const float f_bl = dnf*lff, f_br = dnf*rtf;
    const int ot = up ? -W : 0;                 // clamped row offsets (stay in-bounds)
    const int ob = dn ?  W : 0;
    const int ol = lf ? -1 : 0;
    const int orr= rt ?  4 : 3;

    const float* xp = x + (size_t)(b*C + chunk*CCHUNK) * HW + hw;
    float* pc = part_c + ((size_t)blk*4 + (tid >> 6)) * CCHUNK;

    float4 sum_x = {0,0,0,0}, sum_g = {0,0,0,0};
    float4 max_x = {-INFINITY,-INFINITY,-INFINITY,-INFINITY};
    float4 max_g = {-INFINITY,-INFINITY,-INFINITY,-INFINITY};

    #pragma unroll 2
    for (int cc = 0; cc < CCHUNK; ++cc) {
        const float* q = xp + (size_t)cc * HW;
        float4 t4 = *(const float4*)(q + ot);
        float4 m4 = *(const float4*)(q);
        float4 b4 = *(const float4*)(q + ob);
        float tl = q[ot+ol]*f_tl, tr = q[ot+orr]*f_tr;
        float ml = q[ol]  *lff,   mr = q[orr]  *rtf;
        float bl = q[ob+ol]*f_bl, br = q[ob+orr]*f_br;
        t4.x*=upf; t4.y*=upf; t4.z*=upf; t4.w*=upf;
        b4.x*=dnf; b4.y*=dnf; b4.z*=dnf; b4.w*=dnf;

        const float rt_[6] = { tl, t4.x, t4.y, t4.z, t4.w, tr };
        const float rm_[6] = { ml, m4.x, m4.y, m4.z, m4.w, mr };
        const float rb_[6] = { bl, b4.x, b4.y, b4.z, b4.w, br };

        float g4[4];
        #pragma unroll
        for (int i = 0; i < 4; ++i) {
            // cross-correlation with kx, ky (no flip in XLA conv)
            float gx = 0.25f * ((rt_[i]-rt_[i+2]) + 2.f*(rm_[i]-rm_[i+2]) + (rb_[i]-rb_[i+2]));
            float gy = 0.25f * ((rt_[i]+2.f*rt_[i+1]+rt_[i+2]) - (rb_[i]+2.f*rb_[i+1]+rb_[i+2]));
            g4[i] = sqrtf(gx*gx + gy*gy + 1e-12f);
        }
        sum_x.x += m4.x; sum_x.y += m4.y; sum_x.z += m4.z; sum_x.w += m4.w;
        max_x.x = fmaxf(max_x.x, m4.x); max_x.y = fmaxf(max_x.y, m4.y);
        max_x.z = fmaxf(max_x.z, m4.z); max_x.w = fmaxf(max_x.w, m4.w);
        sum_g.x += g4[0]; sum_g.y += g4[1]; sum_g.z += g4[2]; sum_g.w += g4[3];
        max_g.x = fmaxf(max_g.x, g4[0]); max_g.y = fmaxf(max_g.y, g4[1]);
        max_g.z = fmaxf(max_g.z, g4[2]); max_g.w = fmaxf(max_g.w, g4[3]);

        // wave-level reduce of g over 256 pixels -> private slot (no atomic)
        float gs = (g4[0]+g4[1]) + (g4[2]+g4[3]);
        #pragma unroll
        for (int off = 32; off; off >>= 1) gs += __shfl_xor(gs, off, 64);
        if ((tid & 63) == 0) pc[cc] = gs;
    }

    float* sp = part_s + (size_t)(chunk*B + b) * 4 * HW + hw;
    *(float4*)(sp)        = sum_x;
    *(float4*)(sp +   HW) = max_x;
    *(float4*)(sp + 2*HW) = sum_g;
    *(float4*)(sp + 3*HW) = max_g;
}

// ---------------- k1b: fold 8 channel-chunk partials into s_in ----------------
// thread = one (b, plane, float4). Wave-uniform plane (6400 f4/plane, 64 | 6400).
__global__ __launch_bounds__(256) void k1b_combine(
    const float* __restrict__ part_s, float* __restrict__ s_in)
{
    const int g    = blockIdx.x * 256 + threadIdx.x;   // [0, B*4*F4B)
    const int b    = g / (4*F4B);
    const int rr   = g % (4*F4B);
    const int plane= rr / F4B;
    const int hw   = (rr % F4B) * 4;

    const float* sp0 = part_s + (size_t)b * 4 * HW + plane*HW + hw;
    const size_t cstride = (size_t)B * 4 * HW;

    float4 v = *(const float4*)(sp0);
    if (plane == 0 || plane == 2) {
        #pragma unroll
        for (int c = 1; c < NCHUNK; ++c) {
            float4 u = *(const float4*)(sp0 + c*cstride);
            v.x += u.x; v.y += u.y; v.z += u.z; v.w += u.w;
        }
        v.x *= (1.f/C); v.y *= (1.f/C); v.z *= (1.f/C); v.w *= (1.f/C);
    } else {
        #pragma unroll
        for (int c = 1; c < NCHUNK; ++c) {
            float4 u = *(const float4*)(sp0 + c*cstride);
            v.x = fmaxf(v.x,u.x); v.y = fmaxf(v.y,u.y);
            v.z = fmaxf(v.z,u.z); v.w = fmaxf(v.w,u.w);
        }
    }
    *(float4*)(s_in + (size_t)b * 4 * HW + plane*HW + hw) = v;
}

// ---------------- k2: reduce c partials + channel-gate MLP ----------------
// grid = B blocks; block b reduces 25 pixel-blocks x 4 waves, then the MLP.
__global__ __launch_bounds__(256) void k2_mlp(
    const float* __restrict__ part_c, const float* __restrict__ w1,
    const float* __restrict__ w2, const float* __restrict__ beta,
    float* __restrict__ chanfac)
{
    __shared__ float cv[C];
    __shared__ float hb[HIDDEN];
    const int b   = blockIdx.x;
    const int tid = threadIdx.x;       // = channel index
    const int chunk = tid >> 5;        // which CCHUNK this channel lives in
    const int cc    = tid & (CCHUNK-1);

    float acc = 0.f;
    for (int pbb = 0; pbb < PBB; ++pbb) {
        const int blk = (b*PBB + pbb) * NCHUNK + chunk;
        const float* pcb = part_c + (size_t)blk * 4 * CCHUNK + cc;
        acc += (pcb[0] + pcb[CCHUNK]) + (pcb[2*CCHUNK] + pcb[3*CCHUNK]);
    }
    cv[tid] = acc * (1.f/(float)HW);
    __syncthreads();

    if (tid < HIDDEN) {
        float a = 0.f;
        for (int c = 0; c < C; ++c) a += cv[c] * w1[tid*C + c];
        hb[tid] = fmaxf(a, 0.f);
    }
    __syncthreads();

    float bt = beta[0];
    float sb = (bt > 20.f) ? bt : log1pf(expf(bt));   // softplus
    float a = 0.f;
    #pragma unroll
    for (int j = 0; j < HIDDEN; ++j) a += hb[j] * w2[tid*HIDDEN + j];
    float gate = 1.f / (1.f + expf(-a));
    chanfac[b*C + tid] = 1.f + sb * gate;
}

// ---------------- k3: 7x7 spatial conv + sigmoid ----------------
__global__ __launch_bounds__(256) void k3_spatial(
    const float* __restrict__ s_in, const float* __restrict__ sw,
    const float* __restrict__ sbias, const float* __restrict__ alpha,
    float* __restrict__ sfac)
{
    __shared__ float wgt[4*49];
    const int tid = threadIdx.x;
    if (tid < 196) wgt[tid] = sw[tid];
    __syncthreads();

    const int p  = blockIdx.x * 256 + tid;   // pixel in [0, B*HW)
    const int b  = p / HW;
    const int hw = p % HW;
    const int h  = hw / W;
    const int w  = hw % W;

    const float* base = s_in + (size_t)b * 4 * HW;
    float acc = 0.f;
    for (int ci = 0; ci < 4; ++ci) {
        const float* pl = base + ci*HW;
        #pragma unroll
        for (int i = 0; i < 7; ++i) {
            int hh = h + i - 3;
            if (hh < 0 || hh >= H) continue;
            const float* row = pl + hh*W;
            const float* wr  = wgt + ci*49 + i*7;
            #pragma unroll
            for (int j = 0; j < 7; ++j) {
                int ww = w + j - 3;
                float v = (ww >= 0 && ww < W) ? row[ww] : 0.f;
                acc = fmaf(wr[j], v, acc);
            }
        }
    }
    float al = alpha[0];
    float sa = (al > 20.f) ? al : log1pf(expf(al));   // softplus
    float sg = 1.f / (1.f + expf(-(acc + sbias[0])));
    sfac[p] = 1.f + sa * sg;
}

// ---------------- k4: elementwise combine (float4) ----------------
__global__ __launch_bounds__(256) void k4_combine(
    const float4* __restrict__ x4, const float* __restrict__ sfac,
    const float* __restrict__ chanfac, float4* __restrict__ out4)
{
    const int i = blockIdx.x * 256 + threadIdx.x;  // float4 index
    const int e  = i * 4;
    const int bc = e / HW;          // b*C + c
    const int hw = e % HW;          // aligned to 4 (HW % 4 == 0)
    const int b  = bc / C;

    const float cf = chanfac[bc];
    const float4 s = *(const float4*)&sfac[b*HW + hw];
    float4 xv = x4[i];
    float4 o;
    o.x = xv.x * s.x * cf;
    o.y = xv.y * s.y * cf;
    o.z = xv.z * s.z * cf;
    o.w = xv.w * s.w * cf;
    out4[i] = o;
}

extern "C" void kernel_launch(void* const* d_in, const int* in_sizes, int n_in,
                              void* d_out, int out_size, void* d_ws, size_t ws_size,
                              hipStream_t stream) {
    const float* x     = (const float*)d_in[0];
    const float* w1    = (const float*)d_in[1];
    const float* w2    = (const float*)d_in[2];
    const float* sw    = (const float*)d_in[3];
    const float* sbias = (const float*)d_in[4];
    const float* alpha = (const float*)d_in[5];
    const float* beta  = (const float*)d_in[6];
    float* out = (float*)d_out;

    float* ws = (float*)d_ws;
    // workspace layout (floats):
    float* part_c  = ws;                                      // PBLKS*NCHNK*4*CCHUNK = 204800
    float* part_s  = part_c + (size_t)PBLKS*NCHUNK*4*CCHUNK;  // NCHUNK*B*4*HW = 6553600
    float* s_in    = part_s + (size_t)NCHUNK*B*4*HW;          // B*4*HW = 819200
    float* sfac    = s_in   + (size_t)B*4*HW;                 // B*HW   = 204800
    float* chanfac = sfac   + (size_t)B*HW;                   // B*C    = 2048
    // total = 7,784,448 floats ~= 31.1 MB

    k1_sobel_stats<<<PBLKS*NCHUNK, 256, 0, stream>>>(x, part_c, part_s);
    k1b_combine  <<<(B*4*F4B)/256, 256, 0, stream>>>(part_s, s_in);
    k2_mlp       <<<B,             256, 0, stream>>>(part_c, w1, w2, beta, chanfac);
    k3_spatial   <<<(B*HW)/256,    256, 0, stream>>>(s_in, sw, sbias, alpha, sfac);
    k4_combine   <<<(B*C*HW/4)/256, 256, 0, stream>>>((const float4*)x, sfac, chanfac, (float4*)out);
}